// Round 4
// baseline (203.775 us; speedup 1.0000x reference)
//
#include <hip/hip_runtime.h>

typedef __attribute__((ext_vector_type(8))) short short8;
typedef __attribute__((ext_vector_type(4))) float floatx4;

#define LDS_STRIDE 136  // halfwords/row = 272 B: 16B-aligned rows, b128 frag reads 2-way banked (free)

// PACT integer (q - zp) as exact bf16 bits: |q-zp| <= 256 is exact in bf16, so
// fp32-bit truncation is exact (low 16 bits already zero).
__device__ __forceinline__ unsigned short quant_bf16(float x, float cvn, float cv,
                                                     float scale, float zp) {
    float xc = fminf(fmaxf(x, cvn), cv);
    float q  = rintf(xc * scale + zp);   // RNE, matches jnp.round
    float v  = q - zp;                   // integer in [-256, 256]
    return (unsigned short)(__float_as_uint(v) >> 16);
}

// Fused quant+quant+BMM, v4: only the m2 (transposed) tile goes through LDS.
// m1 fragments are k-contiguous in global -> load 32 B/lane fp32, quantize
// in-register, keep all 16 A-fragments in VGPRs. LDS drops 68->34 KB and the
// barrier only covers B staging => ~3 blocks/CU (12 waves) vs 2 (8 waves).
__global__ __launch_bounds__(256) void fused_qbmm_kernel(
        const float* __restrict__ m1, const float* __restrict__ m2,
        float* __restrict__ C,
        const float* __restrict__ cv1p, const float* __restrict__ cvn1p,
        const float* __restrict__ cv2p, const float* __restrict__ cvn2p) {
    __shared__ __align__(16) unsigned short Bs[128 * LDS_STRIDE];  // [t][d] bf16-int m2^T tile (34 KB)

    const int batch = blockIdx.z;
    const int m0 = blockIdx.y * 128, n0 = blockIdx.x * 128;
    const float* Am = m1 + (size_t)batch * (1024 * 128) + (size_t)m0 * 128;
    const float* Bm = m2 + (size_t)batch * (128 * 1024) + n0;
    float* Cb = C + (size_t)batch * (1024 * 1024);

    const float cv1 = cv1p[0], cvn1 = cvn1p[0];
    const float cv2 = cv2p[0], cvn2 = cvn2p[0];
    const float s1 = 255.0f / (cv1 - cvn1);
    const float zp1 = rintf(-cvn1 * s1);
    const float s2 = 255.0f / (cv2 - cvn2);
    const float zp2 = rintf(-cvn2 * s2);

    const int tid = threadIdx.x;
    const int lane = tid & 63, w = tid >> 6;
    const int wr = w >> 1, wc = w & 1;
    const int row16 = lane & 15, quad = lane >> 4;

    // ---- stage B: m2 tile [128 d][128 t] fp32 -> Bs [t][d] (4x4 in-register transpose) ----
    {
        const int t4 = tid & 31, d0 = tid >> 5;
#pragma unroll
        for (int r = 0; r < 4; ++r) {
            const int d4 = r * 8 + d0;   // d-chunk 0..31
            floatx4 v[4];
#pragma unroll
            for (int i = 0; i < 4; ++i)
                v[i] = *(const floatx4*)(Bm + (size_t)(d4 * 4 + i) * 1024 + t4 * 4);
#pragma unroll
            for (int j = 0; j < 4; ++j) {
                ushort4 wq;
                wq.x = quant_bf16(v[0][j], cvn2, cv2, s2, zp2);
                wq.y = quant_bf16(v[1][j], cvn2, cv2, s2, zp2);
                wq.z = quant_bf16(v[2][j], cvn2, cv2, s2, zp2);
                wq.w = quant_bf16(v[3][j], cvn2, cv2, s2, zp2);
                *(ushort4*)&Bs[(t4 * 4 + j) * LDS_STRIDE + d4 * 4] = wq;  // 8B write
            }
        }
    }

    // ---- A fragments: direct global load (32 B/lane contiguous), quant in-register ----
    // Fragment (for the mfma's B-operand slot): A[s = wr*64+mi*16+row16][k = kk*32+quad*8+j]
    short8 qa[4][4];  // [kk][mi] -- 64 VGPRs
#pragma unroll
    for (int mi = 0; mi < 4; ++mi) {
        const float* ap = Am + (size_t)(wr * 64 + mi * 16 + row16) * 128 + quad * 8;
#pragma unroll
        for (int kk = 0; kk < 4; ++kk) {
            floatx4 v0 = *(const floatx4*)(ap + kk * 32);
            floatx4 v1 = *(const floatx4*)(ap + kk * 32 + 4);
            short8 q;
            q[0] = (short)quant_bf16(v0[0], cvn1, cv1, s1, zp1);
            q[1] = (short)quant_bf16(v0[1], cvn1, cv1, s1, zp1);
            q[2] = (short)quant_bf16(v0[2], cvn1, cv1, s1, zp1);
            q[3] = (short)quant_bf16(v0[3], cvn1, cv1, s1, zp1);
            q[4] = (short)quant_bf16(v1[0], cvn1, cv1, s1, zp1);
            q[5] = (short)quant_bf16(v1[1], cvn1, cv1, s1, zp1);
            q[6] = (short)quant_bf16(v1[2], cvn1, cv1, s1, zp1);
            q[7] = (short)quant_bf16(v1[3], cvn1, cv1, s1, zp1);
            qa[kk][mi] = q;
        }
    }

    __syncthreads();

    // ---- MFMA: 4 waves (2x2), 4x4 16x16x32 tiles/wave, K=128 unrolled ----
    floatx4 acc[4][4] = {};
    const unsigned short* Bbase = &Bs[(wc * 64 + row16) * LDS_STRIDE + quad * 8];

#pragma unroll
    for (int kk = 0; kk < 4; ++kk) {
        short8 b[4];
#pragma unroll
        for (int ni = 0; ni < 4; ++ni)
            b[ni] = *(const short8*)(Bbase + ni * 16 * LDS_STRIDE + kk * 32);  // b128
#pragma unroll
        for (int mi = 0; mi < 4; ++mi)
#pragma unroll
            for (int ni = 0; ni < 4; ++ni)
                // D = (Bt_tile)(A_tile^T) = C^T frag: lane reg r = C[s=row16][t=ni*16+quad*4+r]
                acc[mi][ni] = __builtin_amdgcn_mfma_f32_16x16x32_bf16(
                    b[ni], qa[kk][mi], acc[mi][ni], 0, 0, 0);
    }

    // inv = 1/(scale1*scale2) = (cv1-cvn1)*(cv2-cvn2)/255^2
    const float inv = (cv1 - cvn1) * (cv2 - cvn2) * (1.0f / 65025.0f);

#pragma unroll
    for (int mi = 0; mi < 4; ++mi) {
        float* crow = Cb + (size_t)(m0 + wr * 64 + mi * 16 + row16) * 1024 + n0 + wc * 64;
#pragma unroll
        for (int ni = 0; ni < 4; ++ni) {
            floatx4 o = acc[mi][ni] * inv;
            *(floatx4*)(crow + ni * 16 + quad * 4) = o;   // 16B store
        }
    }
}

extern "C" void kernel_launch(void* const* d_in, const int* in_sizes, int n_in,
                              void* d_out, int out_size, void* d_ws, size_t ws_size,
                              hipStream_t stream) {
    const float* m1   = (const float*)d_in[0];
    const float* m2   = (const float*)d_in[1];
    const float* cv1  = (const float*)d_in[2];
    const float* cvn1 = (const float*)d_in[3];
    const float* cv2  = (const float*)d_in[4];
    const float* cvn2 = (const float*)d_in[5];
    float* out = (float*)d_out;

    // Single fused dispatch: 8x8 C-tiles x 32 batches.
    fused_qbmm_kernel<<<dim3(8, 8, 32), 256, 0, stream>>>(m1, m2, out,
                                                          cv1, cvn1, cv2, cvn2);
}